// Round 1
// 383.812 us; speedup vs baseline: 1.1136x; 1.1136x over previous
//
#include <hip/hip_runtime.h>
#include <cstddef>

// Problem constants
static constexpr int kB    = 256;   // batch
static constexpr int kS    = 196;   // att size (sequence)
static constexpr int kRNN  = 1024;  // rnn size
static constexpr int kATTH = 512;   // att hidden size

__device__ __forceinline__ float fast_tanh(float x) {
    // tanh(x) = (e^{2x}-1)/(e^{2x}+1); clamp so __expf stays finite.
    x = fminf(12.0f, fmaxf(-12.0f, x));
    float e = __expf(2.0f * x);
    return __fdividef(e - 1.0f, e + 1.0f);
}

__device__ __forceinline__ float dot8t(const float4 p0, const float4 p1,
                                       const float4 ah0, const float4 ah1,
                                       const float4 wa0, const float4 wa1) {
    float r;
    r  = fast_tanh(p0.x + ah0.x) * wa0.x;
    r += fast_tanh(p0.y + ah0.y) * wa0.y;
    r += fast_tanh(p0.z + ah0.z) * wa0.z;
    r += fast_tanh(p0.w + ah0.w) * wa0.w;
    r += fast_tanh(p1.x + ah1.x) * wa1.x;
    r += fast_tanh(p1.y + ah1.y) * wa1.y;
    r += fast_tanh(p1.z + ah1.z) * wa1.z;
    r += fast_tanh(p1.w + ah1.w) * wa1.w;
    return r;
}

// Single fused kernel: one block per batch element b, 1024 threads = 16 waves.
// Phase 0: att_h[b,:] = W h_b + bias   (W is L2-resident, coalesced row loads)
// Phase A: scores[s] = sum_a tanh(p[b,s,a] + att_h[a]) * w_alpha[a] + b_alpha
// Phase B: softmax over s (wave 0)
// Phase C: out[b,d] = sum_s weight[s] * att_feats[b,s,d]
__global__ __launch_bounds__(1024) void att_one(
    const float* __restrict__ h,
    const float* __restrict__ att_feats,
    const float* __restrict__ p_att,
    const float* __restrict__ w_h2att,
    const float* __restrict__ b_h2att,
    const float* __restrict__ w_alpha,
    const float* __restrict__ b_alpha,
    float* __restrict__ out) {
    const int b = blockIdx.x;
    const int tid = threadIdx.x;
    const int lane = tid & 63;
    const int wave = tid >> 6;  // 0..15

    __shared__ float sAttH[kATTH];
    __shared__ float sScore[kS];
    __shared__ float4 sRed[3][256];  // phase-C partial sums (groups 1..3)

    // ---- Phase 0: att_h row for this b. Wave w computes rows a = 32w..32w+31.
    {
        const float* hb = &h[(size_t)b * kRNN];
        const int k0 = lane << 2;  // lane covers k0, k0+256, k0+512, k0+768
        const float4 h0 = *(const float4*)&hb[k0];
        const float4 h1 = *(const float4*)&hb[k0 + 256];
        const float4 h2 = *(const float4*)&hb[k0 + 512];
        const float4 h3 = *(const float4*)&hb[k0 + 768];
        const int abase = wave << 5;
#pragma unroll 2
        for (int r = 0; r < 32; ++r) {
            const int a = abase + r;
            const float* wr = &w_h2att[(size_t)a * kRNN + k0];
            const float4 x0 = *(const float4*)(wr);
            const float4 x1 = *(const float4*)(wr + 256);
            const float4 x2 = *(const float4*)(wr + 512);
            const float4 x3 = *(const float4*)(wr + 768);
            float d;
            d  = x0.x * h0.x + x0.y * h0.y + x0.z * h0.z + x0.w * h0.w;
            d += x1.x * h1.x + x1.y * h1.y + x1.z * h1.z + x1.w * h1.w;
            d += x2.x * h2.x + x2.y * h2.y + x2.z * h2.z + x2.w * h2.w;
            d += x3.x * h3.x + x3.y * h3.y + x3.z * h3.z + x3.w * h3.w;
#pragma unroll
            for (int off = 32; off > 0; off >>= 1) d += __shfl_xor(d, off, 64);
            if (lane == 0) sAttH[a] = d + b_h2att[a];
        }
    }
    __syncthreads();

    // ---- Phase A: per-wave score rows; att_h/w_alpha held in registers.
    {
        const int col = lane << 3;  // 8 elements per lane covers ATTH=512
        const float4 ah0 = *(const float4*)&sAttH[col];
        const float4 ah1 = *(const float4*)&sAttH[col + 4];
        const float4 wa0 = *(const float4*)&w_alpha[col];
        const float4 wa1 = *(const float4*)&w_alpha[col + 4];
        const float balpha = b_alpha[0];

        // 2-row unroll: 4 independent 16B loads in flight per lane.
        for (int s = wave; s < kS; s += 32) {
            const int s2 = s + 16;
            const float* p = &p_att[((size_t)b * kS + s) * kATTH + col];
            const float4 p0 = *(const float4*)p;
            const float4 p1 = *(const float4*)(p + 4);
            float4 q0 = {0.f, 0.f, 0.f, 0.f}, q1 = {0.f, 0.f, 0.f, 0.f};
            if (s2 < kS) {
                const float* q = p + (size_t)16 * kATTH;
                q0 = *(const float4*)q;
                q1 = *(const float4*)(q + 4);
            }
            float r1 = dot8t(p0, p1, ah0, ah1, wa0, wa1);
#pragma unroll
            for (int off = 32; off > 0; off >>= 1) r1 += __shfl_xor(r1, off, 64);
            if (lane == 0) sScore[s] = r1 + balpha;
            if (s2 < kS) {
                float r2 = dot8t(q0, q1, ah0, ah1, wa0, wa1);
#pragma unroll
                for (int off = 32; off > 0; off >>= 1) r2 += __shfl_xor(r2, off, 64);
                if (lane == 0) sScore[s2] = r2 + balpha;
            }
        }
    }
    __syncthreads();

    // ---- Phase B: softmax over kS scores, done by wave 0
    if (tid < 64) {
        float vals[4];
        int cnt = 0;
        float m = -3.0e38f;
        for (int s = tid; s < kS; s += 64) {
            vals[cnt] = sScore[s];
            m = fmaxf(m, vals[cnt]);
            ++cnt;
        }
#pragma unroll
        for (int off = 32; off > 0; off >>= 1) m = fmaxf(m, __shfl_xor(m, off, 64));
        float sum = 0.f;
        for (int i = 0; i < cnt; ++i) { vals[i] = __expf(vals[i] - m); sum += vals[i]; }
#pragma unroll
        for (int off = 32; off > 0; off >>= 1) sum += __shfl_xor(sum, off, 64);
        const float inv = __fdividef(1.0f, sum);
        cnt = 0;
        for (int s = tid; s < kS; s += 64) { sScore[s] = vals[cnt] * inv; ++cnt; }
    }
    __syncthreads();

    // ---- Phase C: weighted sum, float4 per thread, 4-way s-split
    const int d4 = tid & 255;  // float4 index over RNN=1024
    const int sg = tid >> 8;   // 0..3  (uniform within a wave)
    const float* af = &att_feats[(size_t)b * kS * kRNN + (d4 << 2)];
    float4 acc = {0.f, 0.f, 0.f, 0.f};
#pragma unroll 4
    for (int i = 0; i < 49; ++i) {  // kS/4 == 49 exactly
        const int s = (i << 2) + sg;
        const float ws = sScore[s];
        const float4 v = *(const float4*)&af[(size_t)s * kRNN];
        acc.x += ws * v.x; acc.y += ws * v.y;
        acc.z += ws * v.z; acc.w += ws * v.w;
    }
    if (sg > 0) sRed[sg - 1][d4] = acc;
    __syncthreads();
    if (sg == 0) {
        const float4 r0 = sRed[0][d4];
        const float4 r1 = sRed[1][d4];
        const float4 r2 = sRed[2][d4];
        acc.x += r0.x + r1.x + r2.x;
        acc.y += r0.y + r1.y + r2.y;
        acc.z += r0.z + r1.z + r2.z;
        acc.w += r0.w + r1.w + r2.w;
        *(float4*)&out[(size_t)b * kRNN + (d4 << 2)] = acc;
    }
}

extern "C" void kernel_launch(void* const* d_in, const int* in_sizes, int n_in,
                              void* d_out, int out_size, void* d_ws, size_t ws_size,
                              hipStream_t stream) {
    const float* h         = (const float*)d_in[0];
    const float* att_feats = (const float*)d_in[1];
    const float* p_att     = (const float*)d_in[2];
    const float* w_h2att   = (const float*)d_in[3];
    const float* b_h2att   = (const float*)d_in[4];
    const float* w_alpha   = (const float*)d_in[5];
    const float* b_alpha   = (const float*)d_in[6];
    float* out = (float*)d_out;

    att_one<<<kB, 1024, 0, stream>>>(h, att_feats, p_att, w_h2att, b_h2att,
                                     w_alpha, b_alpha, out);
}